// Round 9
// baseline (228.557 us; speedup 1.0000x reference)
//
#include <hip/hip_runtime.h>
#include <math.h>

// Problem constants
#define NB   2
#define SEQ  2048
#define CH   768
#define NH   12
#define HD   64
#define F3   2304
#define LSMAX 4.605170185988092f
#define LOG2E 1.4426950408889634f
#define RESCALE_THR 8.0f
#define EXP2F(x) __builtin_amdgcn_exp2f(x)

typedef _Float16 f16;
typedef __attribute__((ext_vector_type(8))) _Float16 f16x8;
typedef __attribute__((ext_vector_type(4))) _Float16 f16x4;
typedef __attribute__((ext_vector_type(2))) _Float16 f16x2;
typedef __attribute__((ext_vector_type(4))) float f32x4;
typedef __attribute__((ext_vector_type(16))) float f32x16;

typedef __attribute__((address_space(3))) void lds_void;
typedef __attribute__((address_space(1))) const void gbl_cvoid;

// f16 workspace layout (units: f16 elements)
#define QSZ   3145728                 // per Q/K/V tensor
#define OATT  (3 * QSZ)               // attn out [N,L,C] f16 (3145728)
#define XHOFF 12582912                // x -> f16 (3145728)
#define W1OFF 15728640                // in_proj_w -> f16 (1769472)
#define W2OFF 17498112                // out_proj_w -> f16 (589824)
#define FLAGO 18087936                // int flag: mask nonzero

// V^T chunked layout: per (n,h) plane = 64 chunks x [64 d][32 k]
#define VCH   2048                    // f16 per chunk (64*32)
#define VPLN  131072                  // f16 per (n,h) plane (HD*SEQ)

// LDS pitch for out_gemm
#define GP2  72

// ---------------------------------------------------------------------------
// fp32 -> f16 convert of X, W1, W2 (one-time). Mask: flag scan. (unchanged)
// ---------------------------------------------------------------------------
__global__ __launch_bounds__(256) void cvt_f16(const float* __restrict__ X,
                                               const float* __restrict__ W1,
                                               const float* __restrict__ W2,
                                               const float* __restrict__ M,
                                               f16* __restrict__ Xh,
                                               f16* __restrict__ W1h,
                                               f16* __restrict__ W2h,
                                               int* __restrict__ flag)
{
    int tid = blockIdx.x * 256 + threadIdx.x;
    if (blockIdx.y == 3) {   // mask: flag-only scan
        if (tid < 1048576) {
            float4 v = ((const float4*)M)[tid];
            bool nz = (v.x != 0.f) || (v.y != 0.f) || (v.z != 0.f) || (v.w != 0.f);
            if (__any(nz) && (threadIdx.x & 63) == 0) atomicOr(flag, 1);
        }
        return;
    }
    const float* src; f16* dst; int n4;
    switch (blockIdx.y) {
        case 0:  src = X;  dst = Xh;  n4 = 786432;  break;
        case 1:  src = W1; dst = W1h; n4 = 442368;  break;
        default: src = W2; dst = W2h; n4 = 147456;  break;
    }
    if (tid < n4) {
        float4 v = ((const float4*)src)[tid];
        f16x4 o = {(f16)v.x, (f16)v.y, (f16)v.z, (f16)v.w};
        ((f16x4*)dst)[tid] = o;
    }
}

// ---------------------------------------------------------------------------
// QKV GEMM (unchanged): V stored in chunked transposed layout;
// Q/K epilogue l2-norm + logit scale folded into Q (log2 domain).
// ---------------------------------------------------------------------------
__global__ __launch_bounds__(256, 4) void qkv_gemm(const f16* __restrict__ Xh,
                                                   const f16* __restrict__ Wh,
                                                   const float* __restrict__ bias,
                                                   const float* __restrict__ logit_scale,
                                                   f16* __restrict__ qkv16)
{
    __shared__ f16 As[2][128 * 32];   // 8 KB per buffer, swizzled
    __shared__ f16 Bs[2][128 * 32];
    const int t    = threadIdx.x;
    const int w    = t >> 6;
    const int lane = t & 63;
    const int quad = lane >> 4;
    const int sub  = lane & 15;
    const int wm   = w & 1, wn = w >> 1;
    const int f0   = blockIdx.x * 128;
    const int m0   = blockIdx.y * 128;

    const int s0 = t, s1 = 256 + t;
    const int r0 = s0 >> 2, cb0 = ((s0 & 3) ^ (r0 & 3)) * 8;
    const int r1 = s1 >> 2, cb1 = ((s1 & 3) ^ (r1 & 3)) * 8;
    const f16* ga0 = Xh + (size_t)(m0 + r0) * CH + cb0;
    const f16* ga1 = Xh + (size_t)(m0 + r1) * CH + cb1;
    const f16* gb0 = Wh + (size_t)(f0 + r0) * CH + cb0;
    const f16* gb1 = Wh + (size_t)(f0 + r1) * CH + cb1;

    f32x4 acc[4][4];
#pragma unroll
    for (int i = 0; i < 4; ++i)
#pragma unroll
        for (int j = 0; j < 4; ++j) acc[i][j] = (f32x4){0.f, 0.f, 0.f, 0.f};

    const int pch = (quad ^ (sub & 3)) * 8;   // f16 offset of 16B chunk

    __builtin_amdgcn_global_load_lds((gbl_cvoid*)(ga0), (lds_void*)&As[0][s0 * 8], 16, 0, 0);
    __builtin_amdgcn_global_load_lds((gbl_cvoid*)(ga1), (lds_void*)&As[0][s1 * 8], 16, 0, 0);
    __builtin_amdgcn_global_load_lds((gbl_cvoid*)(gb0), (lds_void*)&Bs[0][s0 * 8], 16, 0, 0);
    __builtin_amdgcn_global_load_lds((gbl_cvoid*)(gb1), (lds_void*)&Bs[0][s1 * 8], 16, 0, 0);
    __syncthreads();   // drain: buf0 ready

    for (int k0 = 0; k0 < CH; k0 += 32) {
        const int cur = (k0 >> 5) & 1, nxt = cur ^ 1;
        if (k0 + 32 < CH) {
            __builtin_amdgcn_global_load_lds((gbl_cvoid*)(ga0 + k0 + 32), (lds_void*)&As[nxt][s0 * 8], 16, 0, 0);
            __builtin_amdgcn_global_load_lds((gbl_cvoid*)(ga1 + k0 + 32), (lds_void*)&As[nxt][s1 * 8], 16, 0, 0);
            __builtin_amdgcn_global_load_lds((gbl_cvoid*)(gb0 + k0 + 32), (lds_void*)&Bs[nxt][s0 * 8], 16, 0, 0);
            __builtin_amdgcn_global_load_lds((gbl_cvoid*)(gb1 + k0 + 32), (lds_void*)&Bs[nxt][s1 * 8], 16, 0, 0);
        }
        f16x8 af[4], bf[4];
#pragma unroll
        for (int i = 0; i < 4; ++i) {
            af[i] = *(const f16x8*)&As[cur][(wm * 64 + i * 16 + sub) * 32 + pch];
            bf[i] = *(const f16x8*)&Bs[cur][(wn * 64 + i * 16 + sub) * 32 + pch];
        }
#pragma unroll
        for (int i = 0; i < 4; ++i)
#pragma unroll
            for (int j = 0; j < 4; ++j)
                acc[i][j] = __builtin_amdgcn_mfma_f32_16x16x32_f16(af[i], bf[j], acc[i][j], 0, 0, 0);
        __syncthreads();
    }

    const int t3 = f0 / CH;                       // 0=q,1=k,2=v (block-uniform)
    const int h  = ((f0 + wn * 64) % CH) >> 6;    // wave-uniform head
    float bb[4];
#pragma unroll
    for (int j = 0; j < 4; ++j) bb[j] = bias[f0 + wn * 64 + j * 16 + sub];

    if (t3 == 2) {
        // V: chunked transposed store
        f16* vdst = qkv16 + (size_t)2 * QSZ;
#pragma unroll
        for (int i = 0; i < 4; ++i) {
            int mb = m0 + wm * 64 + i * 16 + quad * 4;   // r=0..3 contiguous in l
            int nn = mb >> 11, l0 = mb & 2047;
            f16* pl = vdst + (size_t)(nn * NH + h) * VPLN + (l0 >> 5) * VCH + (l0 & 31);
#pragma unroll
            for (int j = 0; j < 4; ++j) {
                f16x4 vv;
#pragma unroll
                for (int r = 0; r < 4; ++r) vv[r] = (f16)(acc[i][j][r] + bb[j]);
                *(f16x4*)(pl + (j * 16 + sub) * 32) = vv;
            }
        }
        return;
    }

    f16* dst = qkv16 + (size_t)t3 * QSZ;
    float lsv = (t3 == 0) ? __expf(fminf(logit_scale[h], LSMAX)) * LOG2E : 1.0f;
#pragma unroll
    for (int i = 0; i < 4; ++i) {
#pragma unroll
        for (int r = 0; r < 4; ++r) {
            int m = m0 + wm * 64 + i * 16 + quad * 4 + r;
            int n = m >> 11, l = m & 2047;
            float v[4];
#pragma unroll
            for (int j = 0; j < 4; ++j) v[j] = acc[i][j][r] + bb[j];
            float ss = v[0] * v[0] + v[1] * v[1] + v[2] * v[2] + v[3] * v[3];
#pragma unroll
            for (int mk = 1; mk < 16; mk <<= 1) ss += __shfl_xor(ss, mk, 64);
            float scale = 1.0f / fmaxf(sqrtf(ss), 1e-12f);
            if (t3 == 0) scale *= lsv;
            f16* drow = dst + (((size_t)n * NH + h) * SEQ + l) * HD;
#pragma unroll
            for (int j = 0; j < 4; ++j)
                drow[j * 16 + sub] = (f16)(v[j] * scale);
        }
    }
}

// ---------------------------------------------------------------------------
// Flash attention: PURE-REGISTER pipeline (R5 structure, pinned).
//  - Chunked V layout (R5): no 4KB-stride L2 aliasing.
//  - Register double-buffer rotation ka/ua <-> kb/ub, with
//    sched_barrier(0) after each load block: R5's failure was the compiler
//    SINKING the prefetch loads to their uses (VGPR=84); the pin keeps
//    issue before compute, so waits land at first use, post-compute.
//  - NO LDS, NO barriers, NO bank conflicts in the main loop.
//  - __builtin_amdgcn_exp2f (v_exp_f32) everywhere; defer-max THR=8;
//    pkrtz pack; fdot2 l-accum (R8's verified softmax math).
//  - LDS only for the final cross-half merge (~18 KB).
// ---------------------------------------------------------------------------
union V8 { f16x4 h[2]; f16x8 v; };
union U8 { int i[4]; f16x8 v; };

__device__ __forceinline__ void compute_chunk(
    const f16x8& k0f, const f16x8& k1f, const f16x8& k2f, const f16x8& k3f,
    const V8& u0v, const V8& u1v, const V8& u2v, const V8& u3v,
    const f16x8& qf0, const f16x8& qf1, const f16x8& qf2, const f16x8& qf3,
    int cc, bool has_mask, const float* __restrict__ Mg, int h2,
    f32x16& o0, f32x16& o1, float& m_run, float& l_acc)
{
    const f16x2 one2 = {(f16)1.f, (f16)1.f};
    f32x16 sA = {};
    sA = __builtin_amdgcn_mfma_f32_32x32x16_f16(k0f, qf0, sA, 0, 0, 0);
    sA = __builtin_amdgcn_mfma_f32_32x32x16_f16(k1f, qf1, sA, 0, 0, 0);
    sA = __builtin_amdgcn_mfma_f32_32x32x16_f16(k2f, qf2, sA, 0, 0, 0);
    sA = __builtin_amdgcn_mfma_f32_32x32x16_f16(k3f, qf3, sA, 0, 0, 0);
    if (has_mask) {   // rare path
#pragma unroll
        for (int rr = 0; rr < 16; ++rr) {
            int kk = cc * 32 + (rr & 3) + 8 * (rr >> 2) + 4 * h2;
            sA[rr] += LOG2E * Mg[kk];
        }
    }
    // row max: max3-fusable chains + one cross-half shuffle
    float m = fmaxf(fmaxf(sA[0], sA[1]), sA[2]);
    m = fmaxf(fmaxf(m, sA[3]), sA[4]);
    m = fmaxf(fmaxf(m, sA[5]), sA[6]);
    m = fmaxf(fmaxf(m, sA[7]), sA[8]);
    m = fmaxf(fmaxf(m, sA[9]), sA[10]);
    m = fmaxf(fmaxf(m, sA[11]), sA[12]);
    m = fmaxf(fmaxf(m, sA[13]), sA[14]);
    float mloc = fmaxf(m, sA[15]);
    float mfull = fmaxf(mloc, __shfl_xor(mloc, 32, 64));
    // defer-max: rescale only when growth exceeds THR (P stays <= 2^THR)
    if (__any(mfull - m_run > RESCALE_THR)) {
        float mnew = fmaxf(m_run, mfull);
        float al = EXP2F(m_run - mnew);
        m_run = mnew;
        l_acc *= al;
#pragma unroll
        for (int rr = 0; rr < 16; ++rr) { o0[rr] *= al; o1[rr] *= al; }
    }
    // P = exp2(S - m) in-place, pkrtz pack, lane-local frags (sigma order)
#pragma unroll
    for (int rr = 0; rr < 16; ++rr) sA[rr] = EXP2F(sA[rr] - m_run);
    U8 u0, u1;
    u0.i[0] = __builtin_bit_cast(int, __builtin_amdgcn_cvt_pkrtz(sA[0], sA[1]));
    u0.i[1] = __builtin_bit_cast(int, __builtin_amdgcn_cvt_pkrtz(sA[2], sA[3]));
    u0.i[2] = __builtin_bit_cast(int, __builtin_amdgcn_cvt_pkrtz(sA[4], sA[5]));
    u0.i[3] = __builtin_bit_cast(int, __builtin_amdgcn_cvt_pkrtz(sA[6], sA[7]));
    u1.i[0] = __builtin_bit_cast(int, __builtin_amdgcn_cvt_pkrtz(sA[8], sA[9]));
    u1.i[1] = __builtin_bit_cast(int, __builtin_amdgcn_cvt_pkrtz(sA[10], sA[11]));
    u1.i[2] = __builtin_bit_cast(int, __builtin_amdgcn_cvt_pkrtz(sA[12], sA[13]));
    u1.i[3] = __builtin_bit_cast(int, __builtin_amdgcn_cvt_pkrtz(sA[14], sA[15]));
    // l from the SAME f16 P values (lane's own disjoint k-partition)
    l_acc = __builtin_amdgcn_fdot2(__builtin_bit_cast(f16x2, u0.i[0]), one2, l_acc, false);
    l_acc = __builtin_amdgcn_fdot2(__builtin_bit_cast(f16x2, u0.i[1]), one2, l_acc, false);
    l_acc = __builtin_amdgcn_fdot2(__builtin_bit_cast(f16x2, u0.i[2]), one2, l_acc, false);
    l_acc = __builtin_amdgcn_fdot2(__builtin_bit_cast(f16x2, u0.i[3]), one2, l_acc, false);
    l_acc = __builtin_amdgcn_fdot2(__builtin_bit_cast(f16x2, u1.i[0]), one2, l_acc, false);
    l_acc = __builtin_amdgcn_fdot2(__builtin_bit_cast(f16x2, u1.i[1]), one2, l_acc, false);
    l_acc = __builtin_amdgcn_fdot2(__builtin_bit_cast(f16x2, u1.i[2]), one2, l_acc, false);
    l_acc = __builtin_amdgcn_fdot2(__builtin_bit_cast(f16x2, u1.i[3]), one2, l_acc, false);
    // O^T += V^T . P  (slot-wise pairing: both operands in sigma order)
    o0 = __builtin_amdgcn_mfma_f32_32x32x16_f16(u0v.v, u0.v, o0, 0, 0, 0);
    o0 = __builtin_amdgcn_mfma_f32_32x32x16_f16(u1v.v, u1.v, o0, 0, 0, 0);
    o1 = __builtin_amdgcn_mfma_f32_32x32x16_f16(u2v.v, u0.v, o1, 0, 0, 0);
    o1 = __builtin_amdgcn_mfma_f32_32x32x16_f16(u3v.v, u1.v, o1, 0, 0, 0);
}

__global__ __launch_bounds__(256, 3) void attn(const f16* __restrict__ Qh,
                                               const f16* __restrict__ Kh,
                                               const f16* __restrict__ Vt,
                                               const float* __restrict__ M32,
                                               const float* __restrict__ lscale,
                                               const int* __restrict__ flag,
                                               f16* __restrict__ Og)
{
    __shared__ float OS[2][32][68];   // merge-only LDS: 17.4 KB
    __shared__ float MS[2][32];
    __shared__ float LS[2][32];

    const int t    = threadIdx.x;
    const int w    = t >> 6;
    const int lane = t & 63;
    const int g    = w >> 1;          // q-tile (32 q)
    const int s    = w & 1;           // key half (1024 keys)
    const int r32  = lane & 31;
    const int h2   = lane >> 5;
    const int qb   = blockIdx.x * 64;
    const int hh   = blockIdx.y, n = blockIdx.z;
    const bool has_mask = (*flag) != 0;

    const int q = qb + g * 32 + r32;
    const f16* Qg = Qh + ((size_t)(n * NH + hh) * SEQ + q) * HD + 8 * h2;
    const f16* Kl = Kh + ((size_t)(n * NH + hh) * SEQ + s * 1024 + r32) * HD + 8 * h2;
    // chunked V^T: lane base inside chunk = d(r32)*32 + 4*h2 ; chunk stride VCH
    const f16* Vl = Vt + (size_t)(n * NH + hh) * VPLN + (size_t)(s * 32) * VCH
                       + r32 * 32 + 4 * h2;
    const float* Mg = M32 + (size_t)q * SEQ + s * 1024;

    // Q B-frags: Q[q][16t + 8*h2 + e], t = 0..3
    f16x8 qf0 = *(const f16x8*)(Qg + 0);
    f16x8 qf1 = *(const f16x8*)(Qg + 16);
    f16x8 qf2 = *(const f16x8*)(Qg + 32);
    f16x8 qf3 = *(const f16x8*)(Qg + 48);

#define PREF_K(R0, R1, R2, R3, cc) do {                                   \
    const f16* kp_ = Kl + (size_t)((cc) * 32) * HD;                       \
    R0 = *(const f16x8*)(kp_ + 0);  R1 = *(const f16x8*)(kp_ + 16);       \
    R2 = *(const f16x8*)(kp_ + 32); R3 = *(const f16x8*)(kp_ + 48); } while (0)
#define PREF_V(U0, U1, U2, U3, cc) do {                                   \
    const f16* vp_ = Vl + (cc) * VCH;                                     \
    U0.h[0] = *(const f16x4*)(vp_ + 0);    U0.h[1] = *(const f16x4*)(vp_ + 8);    \
    U1.h[0] = *(const f16x4*)(vp_ + 16);   U1.h[1] = *(const f16x4*)(vp_ + 24);   \
    U2.h[0] = *(const f16x4*)(vp_ + 1024); U2.h[1] = *(const f16x4*)(vp_ + 1032); \
    U3.h[0] = *(const f16x4*)(vp_ + 1040); U3.h[1] = *(const f16x4*)(vp_ + 1048); } while (0)

    f16x8 ka0, ka1, ka2, ka3, kb0, kb1, kb2, kb3;
    V8 ua0, ua1, ua2, ua3, ub0, ub1, ub2, ub3;

    f32x16 o0 = {}, o1 = {};          // O^T accum: d-tiles 0-31 / 32-63
    float m_run = -1e30f, l_acc = 0.f;

    PREF_K(ka0, ka1, ka2, ka3, 0);
    PREF_V(ua0, ua1, ua2, ua3, 0);
    __builtin_amdgcn_sched_barrier(0);
#pragma unroll 1
    for (int c = 0; c < 32; c += 2) {
        // issue loads for chunk c+1, pin them above compute of chunk c
        PREF_K(kb0, kb1, kb2, kb3, c + 1);
        PREF_V(ub0, ub1, ub2, ub3, c + 1);
        __builtin_amdgcn_sched_barrier(0);
        compute_chunk(ka0, ka1, ka2, ka3, ua0, ua1, ua2, ua3,
                      qf0, qf1, qf2, qf3, c, has_mask, Mg, h2,
                      o0, o1, m_run, l_acc);
        if (c + 2 < 32) {
            PREF_K(ka0, ka1, ka2, ka3, c + 2);
            PREF_V(ua0, ua1, ua2, ua3, c + 2);
            __builtin_amdgcn_sched_barrier(0);
        }
        compute_chunk(kb0, kb1, kb2, kb3, ub0, ub1, ub2, ub3,
                      qf0, qf1, qf2, qf3, c + 1, has_mask, Mg, h2,
                      o0, o1, m_run, l_acc);
    }
#undef PREF_K
#undef PREF_V

    // cross-half l (each half held a disjoint k-partition)
    float l_full = l_acc + __shfl_xor(l_acc, 32, 64);

    // merge the two key halves (s=1 -> LDS, s=0 merges + stores)
    if (s == 1) {
        if (h2 == 0) { MS[g][r32] = m_run; LS[g][r32] = l_full; }
#pragma unroll
        for (int rq = 0; rq < 4; ++rq) {
            int d0 = 8 * rq + 4 * h2;
            *(f32x4*)&OS[g][r32][d0] =
                (f32x4){o0[rq * 4 + 0], o0[rq * 4 + 1], o0[rq * 4 + 2], o0[rq * 4 + 3]};
            *(f32x4*)&OS[g][r32][d0 + 32] =
                (f32x4){o1[rq * 4 + 0], o1[rq * 4 + 1], o1[rq * 4 + 2], o1[rq * 4 + 3]};
        }
    }
    __syncthreads();
    if (s == 0) {
        float m_p = MS[g][r32], l_p = LS[g][r32];
        float mm = fmaxf(m_run, m_p);
        float a0 = EXP2F(m_run - mm), a1 = EXP2F(m_p - mm);
        float l_tot = a0 * l_full + a1 * l_p;
        float sc = lscale[hh] / l_tot;
        float sa = a0 * sc, sb = a1 * sc;
        f16* op = Og + ((size_t)n * SEQ + q) * CH + hh * 64;
#pragma unroll
        for (int rq = 0; rq < 4; ++rq) {
            int d0 = 8 * rq + 4 * h2;
            f32x4 p0 = *(const f32x4*)&OS[g][r32][d0];
            f32x4 p1 = *(const f32x4*)&OS[g][r32][d0 + 32];
            f16x4 ov0, ov1;
#pragma unroll
            for (int j = 0; j < 4; ++j) {
                ov0[j] = (f16)(o0[rq * 4 + j] * sa + p0[j] * sb);
                ov1[j] = (f16)(o1[rq * 4 + j] * sa + p1[j] * sb);
            }
            *(f16x4*)(op + d0)      = ov0;
            *(f16x4*)(op + 32 + d0) = ov1;
        }
    }
}

// ---------------------------------------------------------------------------
// Output projection (unchanged): 64x64 tile -> 768 blocks = exactly 3/CU.
// ---------------------------------------------------------------------------
__global__ __launch_bounds__(256, 4) void out_gemm(const f16* __restrict__ A,
                                                   const f16* __restrict__ Wh,
                                                   const float* __restrict__ bias,
                                                   float* __restrict__ out)
{
    __shared__ f16 As[64 * GP2];
    __shared__ f16 Bs[64 * GP2];
    const int t    = threadIdx.x;
    const int w    = t >> 6;
    const int lane = t & 63;
    const int quad = lane >> 4;
    const int sub  = lane & 15;
    const int f0   = blockIdx.x * 64;
    const int m0   = blockIdx.y * 64;
    const int srow = t >> 2;            // 0..63
    const int sk   = (t & 3) * 16;      // 0,16,32,48

    const f16* ag = A + (size_t)(m0 + srow) * CH + sk;
    const f16* bg = Wh + (size_t)(f0 + srow) * CH + sk;
    f16x8 a0 = *(const f16x8*)(ag);
    f16x8 a1 = *(const f16x8*)(ag + 8);
    f16x8 b0 = *(const f16x8*)(bg);
    f16x8 b1 = *(const f16x8*)(bg + 8);

    f32x4 acc[4];
#pragma unroll
    for (int i = 0; i < 4; ++i) acc[i] = (f32x4){0.f, 0.f, 0.f, 0.f};

    for (int k0 = 0; k0 < CH; k0 += 64) {
        __syncthreads();
        *(f16x8*)&As[srow * GP2 + sk + 0] = a0;
        *(f16x8*)&As[srow * GP2 + sk + 8] = a1;
        *(f16x8*)&Bs[srow * GP2 + sk + 0] = b0;
        *(f16x8*)&Bs[srow * GP2 + sk + 8] = b1;
        __syncthreads();
        if (k0 + 64 < CH) {
            a0 = *(const f16x8*)(ag + k0 + 64);
            a1 = *(const f16x8*)(ag + k0 + 72);
            b0 = *(const f16x8*)(bg + k0 + 64);
            b1 = *(const f16x8*)(bg + k0 + 72);
        }
#pragma unroll
        for (int kk = 0; kk < 64; kk += 32) {
            f16x8 bf = *(const f16x8*)&Bs[(w * 16 + sub) * GP2 + kk + quad * 8];
#pragma unroll
            for (int i = 0; i < 4; ++i) {
                f16x8 af = *(const f16x8*)&As[(i * 16 + sub) * GP2 + kk + quad * 8];
                acc[i] = __builtin_amdgcn_mfma_f32_16x16x32_f16(af, bf, acc[i], 0, 0, 0);
            }
        }
    }
    float bb = bias[f0 + w * 16 + sub];
#pragma unroll
    for (int i = 0; i < 4; ++i)
#pragma unroll
        for (int r = 0; r < 4; ++r) {
            int m = m0 + i * 16 + quad * 4 + r;
            out[(size_t)m * CH + f0 + w * 16 + sub] = acc[i][r] + bb;
        }
}

extern "C" void kernel_launch(void* const* d_in, const int* in_sizes, int n_in,
                              void* d_out, int out_size, void* d_ws, size_t ws_size,
                              hipStream_t stream) {
    const float* x    = (const float*)d_in[0];
    const float* w1   = (const float*)d_in[1];
    const float* b1   = (const float*)d_in[2];
    const float* ls   = (const float*)d_in[3];
    const float* lrn  = (const float*)d_in[4];
    const float* w2   = (const float*)d_in[5];
    const float* b2   = (const float*)d_in[6];
    const float* msk  = (const float*)d_in[7];
    f16*   ws16 = (f16*)d_ws;
    int*   flag = (int*)(ws16 + FLAGO);
    float* out  = (float*)d_out;

    (void)hipMemsetAsync(flag, 0, 4, stream);
    hipLaunchKernelGGL(cvt_f16, dim3(4096, 4), dim3(256), 0, stream,
                       x, w1, w2, msk,
                       ws16 + XHOFF, ws16 + W1OFF, ws16 + W2OFF, flag);
    hipLaunchKernelGGL(qkv_gemm, dim3(F3 / 128, (NB * SEQ) / 128), dim3(256), 0, stream,
                       ws16 + XHOFF, ws16 + W1OFF, b1, ls, ws16);
    hipLaunchKernelGGL(attn, dim3(SEQ / 64, NH, NB), dim3(256), 0, stream,
                       ws16, ws16 + QSZ, ws16 + 2 * QSZ, msk, lrn, flag,
                       ws16 + OATT);
    hipLaunchKernelGGL(out_gemm, dim3(CH / 64, (NB * SEQ) / 64), dim3(256), 0, stream,
                       ws16 + OATT, ws16 + W2OFF, b2, out);
}

// Round 10
// 188.413 us; speedup vs baseline: 1.2131x; 1.2131x over previous
//
#include <hip/hip_runtime.h>
#include <math.h>

// Problem constants
#define NB   2
#define SEQ  2048
#define CH   768
#define NH   12
#define HD   64
#define F3   2304
#define LSMAX 4.605170185988092f
#define LOG2E 1.4426950408889634f
#define RESCALE_THR 8.0f
#define EXP2F(x) __builtin_amdgcn_exp2f(x)   // bare v_exp_f32 (1ulp); libm exp2f
                                             // is ~15-20 inst OCML (R8/R9 A/B)

typedef _Float16 f16;
typedef __attribute__((ext_vector_type(8))) _Float16 f16x8;
typedef __attribute__((ext_vector_type(4))) _Float16 f16x4;
typedef __attribute__((ext_vector_type(2))) _Float16 f16x2;
typedef __attribute__((ext_vector_type(4))) float f32x4;
typedef __attribute__((ext_vector_type(16))) float f32x16;

typedef __attribute__((address_space(3))) void lds_void;
typedef __attribute__((address_space(1))) const void gbl_cvoid;

// f16 workspace layout (units: f16 elements)
#define QSZ   3145728                 // per Q/K/V tensor
#define OATT  (3 * QSZ)               // attn out [N,L,C] f16 (3145728)
#define XHOFF 12582912                // x -> f16 (3145728)
#define W1OFF 15728640                // in_proj_w -> f16 (1769472)
#define W2OFF 17498112                // out_proj_w -> f16 (589824)
#define FLAGO 18087936                // int flag: mask nonzero

// V^T chunked layout: per (n,h) plane = 64 chunks x [64 d][32 k]
#define VCH   2048                    // f16 per chunk (64*32)
#define VPLN  131072                  // f16 per (n,h) plane (HD*SEQ)

// LDS pitch for out_gemm
#define GP2  72

// attn LDS region offsets (f16 units) within 34816-B shared block
#define KOFF(s, b) (((s) * 2 + (b)) * 2048)
#define VOFF(s, b) (8192 + ((s) * 2 + (b)) * 2304)

// ---------------------------------------------------------------------------
// fp32 -> f16 convert of X, W1, W2 (one-time). Mask: flag scan. (unchanged)
// ---------------------------------------------------------------------------
__global__ __launch_bounds__(256) void cvt_f16(const float* __restrict__ X,
                                               const float* __restrict__ W1,
                                               const float* __restrict__ W2,
                                               const float* __restrict__ M,
                                               f16* __restrict__ Xh,
                                               f16* __restrict__ W1h,
                                               f16* __restrict__ W2h,
                                               int* __restrict__ flag)
{
    int tid = blockIdx.x * 256 + threadIdx.x;
    if (blockIdx.y == 3) {   // mask: flag-only scan
        if (tid < 1048576) {
            float4 v = ((const float4*)M)[tid];
            bool nz = (v.x != 0.f) || (v.y != 0.f) || (v.z != 0.f) || (v.w != 0.f);
            if (__any(nz) && (threadIdx.x & 63) == 0) atomicOr(flag, 1);
        }
        return;
    }
    const float* src; f16* dst; int n4;
    switch (blockIdx.y) {
        case 0:  src = X;  dst = Xh;  n4 = 786432;  break;
        case 1:  src = W1; dst = W1h; n4 = 442368;  break;
        default: src = W2; dst = W2h; n4 = 147456;  break;
    }
    if (tid < n4) {
        float4 v = ((const float4*)src)[tid];
        f16x4 o = {(f16)v.x, (f16)v.y, (f16)v.z, (f16)v.w};
        ((f16x4*)dst)[tid] = o;
    }
}

// ---------------------------------------------------------------------------
// QKV GEMM (unchanged): V stored in chunked transposed layout;
// Q/K epilogue l2-norm + logit scale folded into Q (log2 domain).
// ---------------------------------------------------------------------------
__global__ __launch_bounds__(256, 4) void qkv_gemm(const f16* __restrict__ Xh,
                                                   const f16* __restrict__ Wh,
                                                   const float* __restrict__ bias,
                                                   const float* __restrict__ logit_scale,
                                                   f16* __restrict__ qkv16)
{
    __shared__ f16 As[2][128 * 32];   // 8 KB per buffer, swizzled
    __shared__ f16 Bs[2][128 * 32];
    const int t    = threadIdx.x;
    const int w    = t >> 6;
    const int lane = t & 63;
    const int quad = lane >> 4;
    const int sub  = lane & 15;
    const int wm   = w & 1, wn = w >> 1;
    const int f0   = blockIdx.x * 128;
    const int m0   = blockIdx.y * 128;

    const int s0 = t, s1 = 256 + t;
    const int r0 = s0 >> 2, cb0 = ((s0 & 3) ^ (r0 & 3)) * 8;
    const int r1 = s1 >> 2, cb1 = ((s1 & 3) ^ (r1 & 3)) * 8;
    const f16* ga0 = Xh + (size_t)(m0 + r0) * CH + cb0;
    const f16* ga1 = Xh + (size_t)(m0 + r1) * CH + cb1;
    const f16* gb0 = Wh + (size_t)(f0 + r0) * CH + cb0;
    const f16* gb1 = Wh + (size_t)(f0 + r1) * CH + cb1;

    f32x4 acc[4][4];
#pragma unroll
    for (int i = 0; i < 4; ++i)
#pragma unroll
        for (int j = 0; j < 4; ++j) acc[i][j] = (f32x4){0.f, 0.f, 0.f, 0.f};

    const int pch = (quad ^ (sub & 3)) * 8;   // f16 offset of 16B chunk

    __builtin_amdgcn_global_load_lds((gbl_cvoid*)(ga0), (lds_void*)&As[0][s0 * 8], 16, 0, 0);
    __builtin_amdgcn_global_load_lds((gbl_cvoid*)(ga1), (lds_void*)&As[0][s1 * 8], 16, 0, 0);
    __builtin_amdgcn_global_load_lds((gbl_cvoid*)(gb0), (lds_void*)&Bs[0][s0 * 8], 16, 0, 0);
    __builtin_amdgcn_global_load_lds((gbl_cvoid*)(gb1), (lds_void*)&Bs[0][s1 * 8], 16, 0, 0);
    __syncthreads();   // drain: buf0 ready

    for (int k0 = 0; k0 < CH; k0 += 32) {
        const int cur = (k0 >> 5) & 1, nxt = cur ^ 1;
        if (k0 + 32 < CH) {
            __builtin_amdgcn_global_load_lds((gbl_cvoid*)(ga0 + k0 + 32), (lds_void*)&As[nxt][s0 * 8], 16, 0, 0);
            __builtin_amdgcn_global_load_lds((gbl_cvoid*)(ga1 + k0 + 32), (lds_void*)&As[nxt][s1 * 8], 16, 0, 0);
            __builtin_amdgcn_global_load_lds((gbl_cvoid*)(gb0 + k0 + 32), (lds_void*)&Bs[nxt][s0 * 8], 16, 0, 0);
            __builtin_amdgcn_global_load_lds((gbl_cvoid*)(gb1 + k0 + 32), (lds_void*)&Bs[nxt][s1 * 8], 16, 0, 0);
        }
        f16x8 af[4], bf[4];
#pragma unroll
        for (int i = 0; i < 4; ++i) {
            af[i] = *(const f16x8*)&As[cur][(wm * 64 + i * 16 + sub) * 32 + pch];
            bf[i] = *(const f16x8*)&Bs[cur][(wn * 64 + i * 16 + sub) * 32 + pch];
        }
#pragma unroll
        for (int i = 0; i < 4; ++i)
#pragma unroll
            for (int j = 0; j < 4; ++j)
                acc[i][j] = __builtin_amdgcn_mfma_f32_16x16x32_f16(af[i], bf[j], acc[i][j], 0, 0, 0);
        __syncthreads();
    }

    const int t3 = f0 / CH;                       // 0=q,1=k,2=v (block-uniform)
    const int h  = ((f0 + wn * 64) % CH) >> 6;    // wave-uniform head
    float bb[4];
#pragma unroll
    for (int j = 0; j < 4; ++j) bb[j] = bias[f0 + wn * 64 + j * 16 + sub];

    if (t3 == 2) {
        // V: chunked transposed store
        f16* vdst = qkv16 + (size_t)2 * QSZ;
#pragma unroll
        for (int i = 0; i < 4; ++i) {
            int mb = m0 + wm * 64 + i * 16 + quad * 4;   // r=0..3 contiguous in l
            int nn = mb >> 11, l0 = mb & 2047;
            f16* pl = vdst + (size_t)(nn * NH + h) * VPLN + (l0 >> 5) * VCH + (l0 & 31);
#pragma unroll
            for (int j = 0; j < 4; ++j) {
                f16x4 vv;
#pragma unroll
                for (int r = 0; r < 4; ++r) vv[r] = (f16)(acc[i][j][r] + bb[j]);
                *(f16x4*)(pl + (j * 16 + sub) * 32) = vv;
            }
        }
        return;
    }

    f16* dst = qkv16 + (size_t)t3 * QSZ;
    float lsv = (t3 == 0) ? __expf(fminf(logit_scale[h], LSMAX)) * LOG2E : 1.0f;
#pragma unroll
    for (int i = 0; i < 4; ++i) {
#pragma unroll
        for (int r = 0; r < 4; ++r) {
            int m = m0 + wm * 64 + i * 16 + quad * 4 + r;
            int n = m >> 11, l = m & 2047;
            float v[4];
#pragma unroll
            for (int j = 0; j < 4; ++j) v[j] = acc[i][j][r] + bb[j];
            float ss = v[0] * v[0] + v[1] * v[1] + v[2] * v[2] + v[3] * v[3];
#pragma unroll
            for (int mk = 1; mk < 16; mk <<= 1) ss += __shfl_xor(ss, mk, 64);
            float scale = 1.0f / fmaxf(sqrtf(ss), 1e-12f);
            if (t3 == 0) scale *= lsv;
            f16* drow = dst + (((size_t)n * NH + h) * SEQ + l) * HD;
#pragma unroll
            for (int j = 0; j < 4; ++j)
                drow[j * 16 + sub] = (f16)(v[j] * scale);
        }
    }
}

// ---------------------------------------------------------------------------
// Flash attention. R8 structure (LDS-staged, sink-proof, 70.6us verified)
// with the VALU chain cut that R9 accidentally A/B'd:
//  - EXP2F = __builtin_amdgcn_exp2f (1 inst) replaces libm exp2f (~15-20
//    inst OCML): ~300 VALU inst/chunk removed (R8 VALUBusy 41.9 -> R9 15.6)
//  - row-max as depth-4 tree (max3-fusable) instead of 15-deep serial chain
//  - l accumulated in TWO persistent fdot2 chains (l_accA/B), merged once
//    after the loop (halves the per-chunk serial fdot2 dependency)
// Everything else byte-identical to R8.
// ---------------------------------------------------------------------------
union V8 { f16x4 h[2]; f16x8 v; };
union U8 { int i[4]; f16x8 v; };

__device__ __forceinline__ void compute_chunk_lds(
    const f16* Kr, const f16* Vr, int rsw, int h2,
    const f16x8& qf0, const f16x8& qf1, const f16x8& qf2, const f16x8& qf3,
    int cc, bool has_mask, const float* __restrict__ Mg,
    f32x16& o0, f32x16& o1, float& m_run, float& l_accA, float& l_accB)
{
    const f16x2 one2 = {(f16)1.f, (f16)1.f};
    // K frags from swizzled LDS rows
    f16x8 kf0 = *(const f16x8*)(Kr + ((8 * h2 + 0)  ^ rsw));
    f16x8 kf1 = *(const f16x8*)(Kr + ((8 * h2 + 16) ^ rsw));
    f16x8 kf2 = *(const f16x8*)(Kr + ((8 * h2 + 32) ^ rsw));
    f16x8 kf3 = *(const f16x8*)(Kr + ((8 * h2 + 48) ^ rsw));
    f32x16 sA = {};
    sA = __builtin_amdgcn_mfma_f32_32x32x16_f16(kf0, qf0, sA, 0, 0, 0);
    sA = __builtin_amdgcn_mfma_f32_32x32x16_f16(kf1, qf1, sA, 0, 0, 0);
    sA = __builtin_amdgcn_mfma_f32_32x32x16_f16(kf2, qf2, sA, 0, 0, 0);
    sA = __builtin_amdgcn_mfma_f32_32x32x16_f16(kf3, qf3, sA, 0, 0, 0);
    // V frags (sigma order), pitch-36 LDS rows; d-rows r32 and r32+32
    V8 va, vb, vc, vd;
    va.h[0] = *(const f16x4*)(Vr + 0);
    va.h[1] = *(const f16x4*)(Vr + 8);
    vb.h[0] = *(const f16x4*)(Vr + 16);
    vb.h[1] = *(const f16x4*)(Vr + 24);
    vc.h[0] = *(const f16x4*)(Vr + 1152 + 0);
    vc.h[1] = *(const f16x4*)(Vr + 1152 + 8);
    vd.h[0] = *(const f16x4*)(Vr + 1152 + 16);
    vd.h[1] = *(const f16x4*)(Vr + 1152 + 24);

    if (has_mask) {   // rare path
#pragma unroll
        for (int rr = 0; rr < 16; ++rr) {
            int kk = cc * 32 + (rr & 3) + 8 * (rr >> 2) + 4 * h2;
            sA[rr] += LOG2E * Mg[kk];
        }
    }
    // row max: depth-4 tree (max3-fusable)
    float a0 = fmaxf(sA[0], sA[1]),  a1 = fmaxf(sA[2], sA[3]);
    float a2 = fmaxf(sA[4], sA[5]),  a3 = fmaxf(sA[6], sA[7]);
    float a4 = fmaxf(sA[8], sA[9]),  a5 = fmaxf(sA[10], sA[11]);
    float a6 = fmaxf(sA[12], sA[13]), a7 = fmaxf(sA[14], sA[15]);
    float b0 = fmaxf(a0, a1), b1 = fmaxf(a2, a3);
    float b2 = fmaxf(a4, a5), b3 = fmaxf(a6, a7);
    float mloc = fmaxf(fmaxf(b0, b1), fmaxf(b2, b3));
    float mfull = fmaxf(mloc, __shfl_xor(mloc, 32, 64));
    // defer-max: rescale only when growth exceeds THR (P stays <= 2^THR)
    if (__any(mfull - m_run > RESCALE_THR)) {
        float mnew = fmaxf(m_run, mfull);
        float al = EXP2F(m_run - mnew);
        m_run = mnew;
        l_accA *= al;
        l_accB *= al;
#pragma unroll
        for (int rr = 0; rr < 16; ++rr) { o0[rr] *= al; o1[rr] *= al; }
    }
    // P = exp2(S - m) in-place, pkrtz pack, lane-local frags (sigma order)
#pragma unroll
    for (int rr = 0; rr < 16; ++rr) sA[rr] = EXP2F(sA[rr] - m_run);
    U8 u0, u1;
    u0.i[0] = __builtin_bit_cast(int, __builtin_amdgcn_cvt_pkrtz(sA[0], sA[1]));
    u0.i[1] = __builtin_bit_cast(int, __builtin_amdgcn_cvt_pkrtz(sA[2], sA[3]));
    u0.i[2] = __builtin_bit_cast(int, __builtin_amdgcn_cvt_pkrtz(sA[4], sA[5]));
    u0.i[3] = __builtin_bit_cast(int, __builtin_amdgcn_cvt_pkrtz(sA[6], sA[7]));
    u1.i[0] = __builtin_bit_cast(int, __builtin_amdgcn_cvt_pkrtz(sA[8], sA[9]));
    u1.i[1] = __builtin_bit_cast(int, __builtin_amdgcn_cvt_pkrtz(sA[10], sA[11]));
    u1.i[2] = __builtin_bit_cast(int, __builtin_amdgcn_cvt_pkrtz(sA[12], sA[13]));
    u1.i[3] = __builtin_bit_cast(int, __builtin_amdgcn_cvt_pkrtz(sA[14], sA[15]));
    // l from the SAME f16 P values, two independent chains
    l_accA = __builtin_amdgcn_fdot2(__builtin_bit_cast(f16x2, u0.i[0]), one2, l_accA, false);
    l_accB = __builtin_amdgcn_fdot2(__builtin_bit_cast(f16x2, u0.i[1]), one2, l_accB, false);
    l_accA = __builtin_amdgcn_fdot2(__builtin_bit_cast(f16x2, u0.i[2]), one2, l_accA, false);
    l_accB = __builtin_amdgcn_fdot2(__builtin_bit_cast(f16x2, u0.i[3]), one2, l_accB, false);
    l_accA = __builtin_amdgcn_fdot2(__builtin_bit_cast(f16x2, u1.i[0]), one2, l_accA, false);
    l_accB = __builtin_amdgcn_fdot2(__builtin_bit_cast(f16x2, u1.i[1]), one2, l_accB, false);
    l_accA = __builtin_amdgcn_fdot2(__builtin_bit_cast(f16x2, u1.i[2]), one2, l_accA, false);
    l_accB = __builtin_amdgcn_fdot2(__builtin_bit_cast(f16x2, u1.i[3]), one2, l_accB, false);
    // O^T += V^T . P  (slot-wise pairing: both operands in sigma order)
    o0 = __builtin_amdgcn_mfma_f32_32x32x16_f16(va.v, u0.v, o0, 0, 0, 0);
    o0 = __builtin_amdgcn_mfma_f32_32x32x16_f16(vb.v, u1.v, o0, 0, 0, 0);
    o1 = __builtin_amdgcn_mfma_f32_32x32x16_f16(vc.v, u0.v, o1, 0, 0, 0);
    o1 = __builtin_amdgcn_mfma_f32_32x32x16_f16(vd.v, u1.v, o1, 0, 0, 0);
}

__global__ __launch_bounds__(256, 3) void attn(const f16* __restrict__ Qh,
                                               const f16* __restrict__ Kh,
                                               const f16* __restrict__ Vt,
                                               const float* __restrict__ M32,
                                               const float* __restrict__ lscale,
                                               const int* __restrict__ flag,
                                               f16* __restrict__ Og)
{
    __shared__ f16x8 SMraw[2176];     // 34816 B: K/V staging; OS overlay after
    f16* SM = (f16*)SMraw;

    const int t    = threadIdx.x;
    const int w    = t >> 6;
    const int lane = t & 63;
    const int g    = w >> 1;          // q-tile (32 q)
    const int s    = w & 1;           // key half (1024 keys)
    const int r32  = lane & 31;
    const int h2   = lane >> 5;
    const int qb   = blockIdx.x * 64;
    const int hh   = blockIdx.y, n = blockIdx.z;
    const bool has_mask = (*flag) != 0;

    const int q = qb + g * 32 + r32;
    const f16* Qg  = Qh + ((size_t)(n * NH + hh) * SEQ + q) * HD + 8 * h2;
    const f16* KgH = Kh + ((size_t)(n * NH + hh) * SEQ + s * 1024) * HD;
    const f16* VgH = Vt + (size_t)(n * NH + hh) * VPLN + (size_t)(s * 32) * VCH;
    const float* Mg = M32 + (size_t)q * SEQ + s * 1024;

    // Q B-frags
    f16x8 qf0 = *(const f16x8*)(Qg + 0);
    f16x8 qf1 = *(const f16x8*)(Qg + 16);
    f16x8 qf2 = *(const f16x8*)(Qg + 32);
    f16x8 qf3 = *(const f16x8*)(Qg + 48);

    // staging roles: 128 threads per half (waves g=0,1 of this s)
    const int th   = (g << 6) | lane;          // 0..127
    const int krow = th >> 2;                  // 0..31
    const int kseg = (th & 3) << 4;            // f16 col {0,16,32,48}
    const int ksw  = (krow & 7) << 3;          // write-side XOR (f16 units)
    const int vrow = th >> 1;                  // 0..63
    const int vcol = (th & 1) << 4;            // {0,16}
    const int rsw  = (r32 & 7) << 3;           // read-side XOR

    // loop-invariant LDS base pointers (both buffers)
    f16* Kw0 = SM + KOFF(s, 0) + krow * 64;
    f16* Kw1 = SM + KOFF(s, 1) + krow * 64;
    f16* Vw0 = SM + VOFF(s, 0) + vrow * 36 + vcol;
    f16* Vw1 = SM + VOFF(s, 1) + vrow * 36 + vcol;
    const f16* Kr0 = SM + KOFF(s, 0) + r32 * 64;
    const f16* Kr1 = SM + KOFF(s, 1) + r32 * 64;
    const f16* Vr0 = SM + VOFF(s, 0) + r32 * 36 + 4 * h2;
    const f16* Vr1 = SM + VOFF(s, 1) + r32 * 36 + 4 * h2;

    f16x8 kr0, kr1, vv0, vv1;
    // load + stage chunk 0 into buf 0
    {
        const f16* kp = KgH + krow * 64 + kseg;
        kr0 = *(const f16x8*)(kp);
        kr1 = *(const f16x8*)(kp + 8);
        const f16* vp = VgH + th * 16;
        vv0 = *(const f16x8*)(vp);
        vv1 = *(const f16x8*)(vp + 8);
        *(f16x8*)(Kw0 + ((kseg + 0) ^ ksw)) = kr0;
        *(f16x8*)(Kw0 + ((kseg + 8) ^ ksw)) = kr1;
        *(f16x8*)(Vw0 + 0) = vv0;
        *(f16x8*)(Vw0 + 8) = vv1;
    }
    __syncthreads();

    f32x16 o0 = {}, o1 = {};
    float m_run = -1e30f, l_accA = 0.f, l_accB = 0.f;

#pragma unroll 1
    for (int c = 0; c < 32; c += 2) {
        // ---- sub-iter A: compute buf0, stage chunk c+1 into buf1 ----
        {
            const f16* kp = KgH + ((c + 1) * 32 + krow) * 64 + kseg;
            kr0 = *(const f16x8*)(kp);
            kr1 = *(const f16x8*)(kp + 8);
            const f16* vp = VgH + (c + 1) * VCH + th * 16;
            vv0 = *(const f16x8*)(vp);
            vv1 = *(const f16x8*)(vp + 8);
            __builtin_amdgcn_sched_barrier(0);
        }
        compute_chunk_lds(Kr0, Vr0, rsw, h2, qf0, qf1, qf2, qf3,
                          c, has_mask, Mg, o0, o1, m_run, l_accA, l_accB);
        *(f16x8*)(Kw1 + ((kseg + 0) ^ ksw)) = kr0;   // disjoint buffer: no
        *(f16x8*)(Kw1 + ((kseg + 8) ^ ksw)) = kr1;   // race with buf0 reads
        *(f16x8*)(Vw1 + 0) = vv0;
        *(f16x8*)(Vw1 + 8) = vv1;
        __syncthreads();   // buf1 ready; all buf0 reads done
        // ---- sub-iter B: compute buf1, stage chunk c+2 into buf0 ----
        if (c + 2 < 32) {
            const f16* kp = KgH + ((c + 2) * 32 + krow) * 64 + kseg;
            kr0 = *(const f16x8*)(kp);
            kr1 = *(const f16x8*)(kp + 8);
            const f16* vp = VgH + (c + 2) * VCH + th * 16;
            vv0 = *(const f16x8*)(vp);
            vv1 = *(const f16x8*)(vp + 8);
            __builtin_amdgcn_sched_barrier(0);
        }
        compute_chunk_lds(Kr1, Vr1, rsw, h2, qf0, qf1, qf2, qf3,
                          c + 1, has_mask, Mg, o0, o1, m_run, l_accA, l_accB);
        if (c + 2 < 32) {
            *(f16x8*)(Kw0 + ((kseg + 0) ^ ksw)) = kr0;
            *(f16x8*)(Kw0 + ((kseg + 8) ^ ksw)) = kr1;
            *(f16x8*)(Vw0 + 0) = vv0;
            *(f16x8*)(Vw0 + 8) = vv1;
            __syncthreads();   // buf0 ready
        }
    }

    // merge the two l chains, then cross-half l
    float l_acc = l_accA + l_accB;
    float l_full = l_acc + __shfl_xor(l_acc, 32, 64);

    __syncthreads();   // K/V LDS dead; safe to overlay merge buffers
    float* OSp = (float*)SM;            // [2][32][68]
    float* MSp = OSp + 4352;            // [2][32]
    float* LSp = MSp + 64;              // [2][32]

    if (s == 1) {
        if (h2 == 0) { MSp[g * 32 + r32] = m_run; LSp[g * 32 + r32] = l_full; }
#pragma unroll
        for (int rq = 0; rq < 4; ++rq) {
            int d0 = 8 * rq + 4 * h2;
            *(f32x4*)&OSp[(g * 32 + r32) * 68 + d0] =
                (f32x4){o0[rq * 4 + 0], o0[rq * 4 + 1], o0[rq * 4 + 2], o0[rq * 4 + 3]};
            *(f32x4*)&OSp[(g * 32 + r32) * 68 + d0 + 32] =
                (f32x4){o1[rq * 4 + 0], o1[rq * 4 + 1], o1[rq * 4 + 2], o1[rq * 4 + 3]};
        }
    }
    __syncthreads();
    if (s == 0) {
        float m_p = MSp[g * 32 + r32], l_p = LSp[g * 32 + r32];
        float mm = fmaxf(m_run, m_p);
        float a0 = EXP2F(m_run - mm), a1 = EXP2F(m_p - mm);
        float l_tot = a0 * l_full + a1 * l_p;
        float sc = lscale[hh] / l_tot;
        float sa = a0 * sc, sb = a1 * sc;
        f16* op = Og + ((size_t)n * SEQ + q) * CH + hh * 64;
#pragma unroll
        for (int rq = 0; rq < 4; ++rq) {
            int d0 = 8 * rq + 4 * h2;
            f32x4 p0 = *(const f32x4*)&OSp[(g * 32 + r32) * 68 + d0];
            f32x4 p1 = *(const f32x4*)&OSp[(g * 32 + r32) * 68 + d0 + 32];
            f16x4 ov0, ov1;
#pragma unroll
            for (int j = 0; j < 4; ++j) {
                ov0[j] = (f16)(o0[rq * 4 + j] * sa + p0[j] * sb);
                ov1[j] = (f16)(o1[rq * 4 + j] * sa + p1[j] * sb);
            }
            *(f16x4*)(op + d0)      = ov0;
            *(f16x4*)(op + 32 + d0) = ov1;
        }
    }
}

// ---------------------------------------------------------------------------
// Output projection (unchanged): 64x64 tile -> 768 blocks = exactly 3/CU.
// ---------------------------------------------------------------------------
__global__ __launch_bounds__(256, 4) void out_gemm(const f16* __restrict__ A,
                                                   const f16* __restrict__ Wh,
                                                   const float* __restrict__ bias,
                                                   float* __restrict__ out)
{
    __shared__ f16 As[64 * GP2];
    __shared__ f16 Bs[64 * GP2];
    const int t    = threadIdx.x;
    const int w    = t >> 6;
    const int lane = t & 63;
    const int quad = lane >> 4;
    const int sub  = lane & 15;
    const int f0   = blockIdx.x * 64;
    const int m0   = blockIdx.y * 64;
    const int srow = t >> 2;            // 0..63
    const int sk   = (t & 3) * 16;      // 0,16,32,48

    const f16* ag = A + (size_t)(m0 + srow) * CH + sk;
    const f16* bg = Wh + (size_t)(f0 + srow) * CH + sk;
    f16x8 a0 = *(const f16x8*)(ag);
    f16x8 a1 = *(const f16x8*)(ag + 8);
    f16x8 b0 = *(const f16x8*)(bg);
    f16x8 b1 = *(const f16x8*)(bg + 8);

    f32x4 acc[4];
#pragma unroll
    for (int i = 0; i < 4; ++i) acc[i] = (f32x4){0.f, 0.f, 0.f, 0.f};

    for (int k0 = 0; k0 < CH; k0 += 64) {
        __syncthreads();
        *(f16x8*)&As[srow * GP2 + sk + 0] = a0;
        *(f16x8*)&As[srow * GP2 + sk + 8] = a1;
        *(f16x8*)&Bs[srow * GP2 + sk + 0] = b0;
        *(f16x8*)&Bs[srow * GP2 + sk + 8] = b1;
        __syncthreads();
        if (k0 + 64 < CH) {
            a0 = *(const f16x8*)(ag + k0 + 64);
            a1 = *(const f16x8*)(ag + k0 + 72);
            b0 = *(const f16x8*)(bg + k0 + 64);
            b1 = *(const f16x8*)(bg + k0 + 72);
        }
#pragma unroll
        for (int kk = 0; kk < 64; kk += 32) {
            f16x8 bf = *(const f16x8*)&Bs[(w * 16 + sub) * GP2 + kk + quad * 8];
#pragma unroll
            for (int i = 0; i < 4; ++i) {
                f16x8 af = *(const f16x8*)&As[(i * 16 + sub) * GP2 + kk + quad * 8];
                acc[i] = __builtin_amdgcn_mfma_f32_16x16x32_f16(af, bf, acc[i], 0, 0, 0);
            }
        }
    }
    float bb = bias[f0 + w * 16 + sub];
#pragma unroll
    for (int i = 0; i < 4; ++i)
#pragma unroll
        for (int r = 0; r < 4; ++r) {
            int m = m0 + i * 16 + quad * 4 + r;
            out[(size_t)m * CH + f0 + w * 16 + sub] = acc[i][r] + bb;
        }
}

extern "C" void kernel_launch(void* const* d_in, const int* in_sizes, int n_in,
                              void* d_out, int out_size, void* d_ws, size_t ws_size,
                              hipStream_t stream) {
    const float* x    = (const float*)d_in[0];
    const float* w1   = (const float*)d_in[1];
    const float* b1   = (const float*)d_in[2];
    const float* ls   = (const float*)d_in[3];
    const float* lrn  = (const float*)d_in[4];
    const float* w2   = (const float*)d_in[5];
    const float* b2   = (const float*)d_in[6];
    const float* msk  = (const float*)d_in[7];
    f16*   ws16 = (f16*)d_ws;
    int*   flag = (int*)(ws16 + FLAGO);
    float* out  = (float*)d_out;

    (void)hipMemsetAsync(flag, 0, 4, stream);
    hipLaunchKernelGGL(cvt_f16, dim3(4096, 4), dim3(256), 0, stream,
                       x, w1, w2, msk,
                       ws16 + XHOFF, ws16 + W1OFF, ws16 + W2OFF, flag);
    hipLaunchKernelGGL(qkv_gemm, dim3(F3 / 128, (NB * SEQ) / 128), dim3(256), 0, stream,
                       ws16 + XHOFF, ws16 + W1OFF, b1, ls, ws16);
    hipLaunchKernelGGL(attn, dim3(SEQ / 64, NH, NB), dim3(256), 0, stream,
                       ws16, ws16 + QSZ, ws16 + 2 * QSZ, msk, lrn, flag,
                       ws16 + OATT);
    hipLaunchKernelGGL(out_gemm, dim3(CH / 64, (NB * SEQ) / 64), dim3(256), 0, stream,
                       ws16 + OATT, ws16 + W2OFF, b2, out);
}